// Round 6
// baseline (382.384 us; speedup 1.0000x reference)
//
#include <hip/hip_runtime.h>
#include <cstdint>
#include <cstddef>

typedef __bf16 bf16;
typedef __attribute__((ext_vector_type(8))) __bf16 bf16x8;
typedef __attribute__((ext_vector_type(4))) float f32x4;
typedef __attribute__((ext_vector_type(4))) unsigned short u16x4;
typedef __attribute__((ext_vector_type(8))) unsigned short u16x8;

#define DEV __device__ __forceinline__

// fp32 -> bf16 round-to-nearest-even (explicit, deterministic)
DEV unsigned short f2bf(float f) {
    unsigned int u = __builtin_bit_cast(unsigned int, f);
    u += 0x7FFFu + ((u >> 16) & 1u);
    return (unsigned short)(u >> 16);
}

DEV float bf2f(unsigned short h) {
    unsigned int u = ((unsigned int)h) << 16;
    return __builtin_bit_cast(float, u);
}

// async global->LDS, 16B per lane; lds base must be wave-uniform (HW adds lane*16)
DEV void gload16(const void* g, void* l) {
    __builtin_amdgcn_global_load_lds(
        (const __attribute__((address_space(1))) unsigned int*)g,
        (__attribute__((address_space(3))) unsigned int*)l, 16, 0, 0);
}

DEV f32x4 mfma16(bf16x8 a, bf16x8 b, f32x4 c) {
    return __builtin_amdgcn_mfma_f32_16x16x32_bf16(a, b, c, 0, 0, 0);
}

// ---------------------------------------------------------------------------
// K0: weight conversion. q-rows of w_qkv get softmax scale (1/16) * log2(e)
// folded in, so attention logits are already in log2 domain.
// ---------------------------------------------------------------------------
__global__ void k_wconv(const float* __restrict__ wqkv, const float* __restrict__ wproj,
                        unsigned short* __restrict__ wq, unsigned short* __restrict__ wp) {
    int i = blockIdx.x * 256 + threadIdx.x;   // grid covers 768*256 + 256*256 exactly
    if (i < 768 * 256) {
        float v = wqkv[i];
        if (i < 256 * 256) v *= 0.09016844005556022f;  // (1/16)*log2(e)
        wq[i] = f2bf(v);
    } else {
        int j = i - 768 * 256;
        wp[j] = f2bf(wproj[j]);
    }
}

// ---------------------------------------------------------------------------
// K1: GroupNorm stats. One block per (b, group): 8 channels * 4096 = 32768 f32.
// ---------------------------------------------------------------------------
__global__ __launch_bounds__(256) void k_gnstats(const float* __restrict__ x,
                                                 float* __restrict__ stats) {
    int bg = blockIdx.x;  // b*32 + g
    const float4* xp = (const float4*)(x + (size_t)bg * 32768);
    int t = threadIdx.x;
    float s = 0.f, sq = 0.f;
    #pragma unroll 4
    for (int i = 0; i < 32; ++i) {
        float4 v = xp[t + i * 256];
        s  += v.x + v.y + v.z + v.w;
        sq += v.x * v.x + v.y * v.y + v.z * v.z + v.w * v.w;
    }
    #pragma unroll
    for (int m = 1; m < 64; m <<= 1) { s += __shfl_xor(s, m); sq += __shfl_xor(sq, m); }
    __shared__ float red[8];
    int w = t >> 6;
    if ((t & 63) == 0) { red[w] = s; red[4 + w] = sq; }
    __syncthreads();
    if (t == 0) {
        s  = red[0] + red[1] + red[2] + red[3];
        sq = red[4] + red[5] + red[6] + red[7];
        float mean = s * (1.f / 32768.f);
        float var  = sq * (1.f / 32768.f) - mean * mean;
        stats[bg * 2]     = mean;
        stats[bg * 2 + 1] = rsqrtf(var + 1e-5f);
    }
}

// ---------------------------------------------------------------------------
// K2: apply GroupNorm -> xn fp32 (b,c,n) [residual] + xnT bf16 (b,n,c) [GEMM A]
// ---------------------------------------------------------------------------
__global__ __launch_bounds__(256) void k_gnapply(const float* __restrict__ x,
        const float* __restrict__ scale, const float* __restrict__ bias,
        const float* __restrict__ stats, float* __restrict__ xn,
        unsigned short* __restrict__ xnT) {
    __shared__ __align__(16) unsigned short tsm[64][72];
    int t = threadIdx.x;
    int nb = blockIdx.x * 64, cb = blockIdx.y * 64, b = blockIdx.z;
    int cl = t >> 2, nc = (t & 3) * 16;
    int cg = cb + cl;
    float mean = stats[(b * 32 + (cg >> 3)) * 2];
    float rstd = stats[(b * 32 + (cg >> 3)) * 2 + 1];
    float sc = scale[cg] * rstd;
    float bi = bias[cg] - mean * sc;      // xn = x*sc + bi
    const float4* xrow = (const float4*)(x  + ((size_t)(b * 256 + cg)) * 4096 + nb + nc);
    float4*      orow  = (float4*)      (xn + ((size_t)(b * 256 + cg)) * 4096 + nb + nc);
    #pragma unroll
    for (int j = 0; j < 4; ++j) {
        float4 v = xrow[j];
        v.x = v.x * sc + bi; v.y = v.y * sc + bi; v.z = v.z * sc + bi; v.w = v.w * sc + bi;
        orow[j] = v;
        u16x4 us;
        us[0] = f2bf(v.x); us[1] = f2bf(v.y); us[2] = f2bf(v.z); us[3] = f2bf(v.w);
        *(u16x4*)&tsm[cl][nc + j * 4] = us;
    }
    __syncthreads();
    int nl = t >> 2, cc = (t & 3) * 16;
    u16x8 o0, o1;
    #pragma unroll
    for (int j = 0; j < 8; ++j) { o0[j] = tsm[cc + j][nl]; o1[j] = tsm[cc + 8 + j][nl]; }
    unsigned short* dst = xnT + ((size_t)(b * 4096 + nb + nl)) * 256 + cb + cc;
    *(u16x8*)dst = o0;
    *(u16x8*)(dst + 8) = o1;
}

// ---------------------------------------------------------------------------
// K3: QKV GEMM. qkvT(16384, 768) = xnT(16384,256) @ w_qkv^T.  64x64 tile, K=256.
// ---------------------------------------------------------------------------
__global__ __launch_bounds__(256) void k_qkv(const unsigned short* __restrict__ xnT,
        const unsigned short* __restrict__ wq, unsigned short* __restrict__ qkvT) {
    __shared__ __align__(16) char smem[65536];
    char* Asm = smem;
    char* Bsm = smem + 32768;
    int t = threadIdx.x, l = t & 63, w = t >> 6;
    int mb = blockIdx.x * 64, nb = blockIdx.y * 64;
    #pragma unroll
    for (int i = 0; i < 8; ++i) {
        int idx = (w * 8 + i) * 64 + l;
        int r = idx >> 5, p = idx & 31;
        gload16(xnT + (size_t)(mb + r) * 256 + ((p ^ (r & 7)) * 8), Asm + (w * 8 + i) * 1024);
    }
    #pragma unroll
    for (int i = 0; i < 8; ++i) {
        int idx = (w * 8 + i) * 64 + l;
        int r = idx >> 5, p = idx & 31;
        gload16(wq + (size_t)(nb + r) * 256 + ((p ^ (r & 7)) * 8), Bsm + (w * 8 + i) * 1024);
    }
    __syncthreads();
    int arow = w * 16 + (l & 15);
    bf16x8 af[8];
    #pragma unroll
    for (int ks = 0; ks < 8; ++ks)
        af[ks] = *(const bf16x8*)(Asm + arow * 512 + (((ks * 4 + (l >> 4)) ^ (arow & 7)) << 4));
    f32x4 acc[4];
    #pragma unroll
    for (int i = 0; i < 4; ++i) acc[i] = f32x4{0.f, 0.f, 0.f, 0.f};
    #pragma unroll
    for (int sub = 0; sub < 4; ++sub) {
        int brow = sub * 16 + (l & 15);
        #pragma unroll
        for (int ks = 0; ks < 8; ++ks) {
            bf16x8 bb = *(const bf16x8*)(Bsm + brow * 512 + (((ks * 4 + (l >> 4)) ^ (brow & 7)) << 4));
            acc[sub] = mfma16(af[ks], bb, acc[sub]);
        }
    }
    int row0 = mb + w * 16 + (l >> 4) * 4;
    #pragma unroll
    for (int sub = 0; sub < 4; ++sub) {
        #pragma unroll
        for (int r = 0; r < 4; ++r)
            qkvT[(size_t)(row0 + r) * 768 + nb + sub * 16 + (l & 15)] = f2bf(acc[sub][r]);
    }
}

// ---------------------------------------------------------------------------
// K4: transpose V from qkvT cols [512,768) (b,n,c) -> vT (b,c,n) bf16
// ---------------------------------------------------------------------------
__global__ __launch_bounds__(256) void k_vtrans(const unsigned short* __restrict__ qkvT,
                                                unsigned short* __restrict__ vT) {
    __shared__ __align__(16) unsigned short tsm[64][72];
    int t = threadIdx.x;
    int nb = blockIdx.x * 64, cb = blockIdx.y * 64, b = blockIdx.z;
    int nl = t >> 2, cc = (t & 3) * 16;
    const unsigned short* src = qkvT + (size_t)(b * 4096 + nb + nl) * 768 + 512 + cb + cc;
    u16x8 v0 = *(const u16x8*)src;
    u16x8 v1 = *(const u16x8*)(src + 8);
    *(u16x8*)&tsm[nl][cc] = v0;
    *(u16x8*)&tsm[nl][cc + 8] = v1;
    __syncthreads();
    int clc = t >> 2, nn = (t & 3) * 16;
    u16x8 o0, o1;
    #pragma unroll
    for (int j = 0; j < 8; ++j) { o0[j] = tsm[nn + j][clc]; o1[j] = tsm[nn + 8 + j][clc]; }
    unsigned short* dst = vT + (size_t)(b * 256 + cb + clc) * 4096 + nb + nn;
    *(u16x8*)dst = o0;
    *(u16x8*)(dst + 8) = o1;
}

// ---------------------------------------------------------------------------
// K5: flash attention v3 — LDS-read amortization.
// 512 threads = 8 waves: wave = (qg in 0..3, kh in 0..1). Each wave computes
// 32 q-rows (2 groups of 16) x its 32-kv HALF of each 64-kv tile: every
// kb/vb ds_read feeds 2 MFMA, and each wave reads only half the K/V rows
// (34 reads/wave/tile vs 66 in v2 -> LDS-pipe bound drops ~1.5x).
// QBLK=128, KVBLK=64, kv-split x2, grid=256 (1 block/CU), XCD decode bid&7.
// LDS 144KB: K dbuf 2x32K, V dbuf 2x32K, P 8x2KB @131072.
// kv-half merge at end through LDS (m/l + acc exchange over dead K/V).
// Q pre-scaled by (1/16)*log2(e); defer-max THR=8; row-sum via ones-MFMA.
// ---------------------------------------------------------------------------
struct AttnState {
    f32x4 acc0[16], acc1[16];
    f32x4 sum0, sum1;
    float m0[4], m1[4];
};

#define SM_GROUP(SG, MG, ACCG, SUMG, GBASE)                                      \
    do {                                                                         \
        float tm[4];                                                             \
        _Pragma("unroll")                                                        \
        for (int r = 0; r < 4; ++r) {                                            \
            float v = fmaxf(SG[0][r], SG[1][r]);                                 \
            _Pragma("unroll")                                                    \
            for (int mm = 1; mm < 16; mm <<= 1) v = fmaxf(v, __shfl_xor(v, mm)); \
            tm[r] = v;                                                           \
        }                                                                        \
        int defer = 1;                                                           \
        _Pragma("unroll")                                                        \
        for (int r = 0; r < 4; ++r) defer &= (tm[r] <= MG[r] + 8.f) ? 1 : 0;     \
        if (!__all(defer)) {                                                     \
            float sf[4];                                                         \
            _Pragma("unroll")                                                    \
            for (int r = 0; r < 4; ++r) {                                        \
                float mn = fmaxf(MG[r], tm[r]);                                  \
                sf[r] = __builtin_amdgcn_exp2f(MG[r] - mn);                      \
                MG[r] = mn;                                                      \
            }                                                                    \
            _Pragma("unroll")                                                    \
            for (int i = 0; i < 16; ++i) {                                       \
                ACCG[i][0] *= sf[0]; ACCG[i][1] *= sf[1];                        \
                ACCG[i][2] *= sf[2]; ACCG[i][3] *= sf[3];                        \
            }                                                                    \
            SUMG[0] *= sf[0]; SUMG[1] *= sf[1];                                  \
            SUMG[2] *= sf[2]; SUMG[3] *= sf[3];                                  \
        }                                                                        \
        _Pragma("unroll")                                                        \
        for (int jt = 0; jt < 2; ++jt) {                                         \
            _Pragma("unroll")                                                    \
            for (int r = 0; r < 4; ++r) {                                        \
                float pv = __builtin_amdgcn_exp2f(SG[jt][r] - MG[r]);            \
                int row = (GBASE) + (l >> 4) * 4 + r;                            \
                int col = jt * 16 + (l & 15);                                    \
                int bo = row * 64 + (((col >> 3) ^ (row & 3)) << 4) + (col & 7) * 2; \
                *(unsigned short*)(Psm + bo) = f2bf(pv);                         \
            }                                                                    \
        }                                                                        \
    } while (0)

DEV void attn_step(const char* Ksm, const char* Vsm, char* Psm,
                   const bf16x8 qf0[8], const bf16x8 qf1[8],
                   AttnState& st, int l, int kh) {
    // QK^T for both q-groups off one kb read (log2 domain)
    f32x4 s0[2], s1[2];
    __builtin_amdgcn_s_setprio(1);
    #pragma unroll
    for (int jt = 0; jt < 2; ++jt) {
        f32x4 a0 = f32x4{0.f, 0.f, 0.f, 0.f};
        f32x4 a1 = f32x4{0.f, 0.f, 0.f, 0.f};
        int jr = kh * 32 + jt * 16 + (l & 15);
        #pragma unroll
        for (int ks = 0; ks < 8; ++ks) {
            bf16x8 kb = *(const bf16x8*)(Ksm + jr * 512 + (((ks * 4 + (l >> 4)) ^ (jr & 7)) << 4));
            a0 = mfma16(qf0[ks], kb, a0);
            a1 = mfma16(qf1[ks], kb, a1);
        }
        s0[jt] = a0; s1[jt] = a1;
    }
    __builtin_amdgcn_s_setprio(0);

    SM_GROUP(s0, st.m0, st.acc0, st.sum0, 0);
    SM_GROUP(s1, st.m1, st.acc1, st.sum1, 16);

    asm volatile("s_waitcnt lgkmcnt(0)" ::: "memory");
    __builtin_amdgcn_sched_barrier(0);

    // O += P · V over this wave's 32-kv half; both groups share each vb read.
    bf16x8 onesv;
    #pragma unroll
    for (int j = 0; j < 8; ++j) onesv[j] = (__bf16)1.0f;
    int rp0 = (l & 15), rp1 = 16 + (l & 15);
    bf16x8 pa0 = *(const bf16x8*)(Psm + rp0 * 64 + (((l >> 4) ^ (rp0 & 3)) << 4));
    bf16x8 pa1 = *(const bf16x8*)(Psm + rp1 * 64 + (((l >> 4) ^ (rp1 & 3)) << 4));
    __builtin_amdgcn_s_setprio(1);
    #pragma unroll
    for (int sub = 0; sub < 16; ++sub) {
        int cr = sub * 16 + (l & 15);
        bf16x8 vb = *(const bf16x8*)(Vsm + cr * 128 + (((kh * 4 + (l >> 4)) ^ (cr & 7)) << 4));
        st.acc0[sub] = mfma16(pa0, vb, st.acc0[sub]);
        st.acc1[sub] = mfma16(pa1, vb, st.acc1[sub]);
    }
    st.sum0 = mfma16(pa0, onesv, st.sum0);
    st.sum1 = mfma16(pa1, onesv, st.sum1);
    __builtin_amdgcn_s_setprio(0);
}

#define ATTN_STAGE(KN, VN, kvn)                                                   \
    do {                                                                          \
        _Pragma("unroll")                                                         \
        for (int i_ = 0; i_ < 4; ++i_) {                                          \
            int e_ = (w * 4 + i_) * 64 + l;                                       \
            int r_ = e_ >> 5, p_ = e_ & 31;                                       \
            gload16(kg0 + (size_t)((kvn) + r_) * 768 + ((p_ ^ (r_ & 7)) * 8),     \
                    (KN) + (w * 4 + i_) * 1024);                                  \
        }                                                                         \
        _Pragma("unroll")                                                         \
        for (int i_ = 0; i_ < 4; ++i_) {                                          \
            int e_ = (w * 4 + i_) * 64 + l;                                       \
            int r_ = e_ >> 3, p_ = e_ & 7;                                        \
            gload16(vg0 + (size_t)r_ * 4096 + (kvn) + ((p_ ^ (r_ & 7)) * 8),      \
                    (VN) + (w * 4 + i_) * 1024);                                  \
        }                                                                         \
    } while (0)

__global__ __launch_bounds__(512, 2) void k_attn(const unsigned short* __restrict__ qkvT,
        const unsigned short* __restrict__ vT, unsigned short* __restrict__ Opart,
        float* __restrict__ ml) {
    __shared__ __align__(16) char smem[147456];
    char* Ksm0 = smem;
    char* Vsm0 = smem + 32768;
    char* Ksm1 = smem + 65536;
    char* Vsm1 = smem + 98304;
    int t = threadIdx.x, l = t & 63, w = t >> 6;   // w in 0..7
    int qg = w & 3, kh = w >> 2;
    char* Psm = smem + 131072 + w * 2048;          // per-wave 32x32 P
    int bid = blockIdx.x;
    int combo = bid & 7;
    int b = combo >> 1;
    int half = combo & 1;
    int qb = (bid >> 3) * 128;
    int kv0 = half * 2048;

    int qbase = qb + qg * 32;
    const unsigned short* qr0 =
        qkvT + (size_t)(b * 4096 + qbase + (l & 15)) * 768 + (l >> 4) * 8;
    const unsigned short* qr1 = qr0 + (size_t)16 * 768;
    bf16x8 qf0[8], qf1[8];
    #pragma unroll
    for (int ks = 0; ks < 8; ++ks) {
        qf0[ks] = *(const bf16x8*)(qr0 + ks * 32);
        qf1[ks] = *(const bf16x8*)(qr1 + ks * 32);
    }

    AttnState st;
    #pragma unroll
    for (int i = 0; i < 16; ++i) {
        st.acc0[i] = f32x4{0.f, 0.f, 0.f, 0.f};
        st.acc1[i] = f32x4{0.f, 0.f, 0.f, 0.f};
    }
    st.sum0 = f32x4{0.f, 0.f, 0.f, 0.f};
    st.sum1 = f32x4{0.f, 0.f, 0.f, 0.f};
    #pragma unroll
    for (int r = 0; r < 4; ++r) { st.m0[r] = -3.0e38f; st.m1[r] = -3.0e38f; }

    const unsigned short* kg0 = qkvT + (size_t)(b * 4096) * 768 + 256;
    const unsigned short* vg0 = vT + (size_t)(b * 256) * 4096;

    ATTN_STAGE(Ksm0, Vsm0, kv0);
    __syncthreads();

    for (int kv = kv0; kv < kv0 + 2048; kv += 128) {
        ATTN_STAGE(Ksm1, Vsm1, kv + 64);
        attn_step(Ksm0, Vsm0, Psm, qf0, qf1, st, l, kh);
        __syncthreads();
        int kvn2 = (kv + 128 < kv0 + 2048) ? (kv + 128) : kv0;  // last: harmless re-stage
        ATTN_STAGE(Ksm0, Vsm0, kvn2);
        attn_step(Ksm1, Vsm1, Psm, qf0, qf1, st, l, kh);
        __syncthreads();
    }

    // ---- kv-half merge: waves (qg, kh=1) hand state to (qg, kh=0) via LDS ----
    float* mlS  = (float*)smem;           // [qg*2+g][row16][{m,l}]  (1KB, dead K region)
    float* accS = (float*)(smem + 4096);  // [(qg*2+g)][sub16][col16][r4] f32 (128KB)
    if (kh == 1) {
        if ((l & 15) == 0) {
            #pragma unroll
            for (int r = 0; r < 4; ++r) {
                int row = (l >> 4) * 4 + r;
                mlS[((qg * 2 + 0) * 16 + row) * 2]     = st.m0[r];
                mlS[((qg * 2 + 0) * 16 + row) * 2 + 1] = st.sum0[r];
                mlS[((qg * 2 + 1) * 16 + row) * 2]     = st.m1[r];
                mlS[((qg * 2 + 1) * 16 + row) * 2 + 1] = st.sum1[r];
            }
        }
        #pragma unroll
        for (int sub = 0; sub < 16; ++sub) {
            float* p0 = accS + (qg * 2 + 0) * 4096 + sub * 256 + (l & 15) * 16 + (l >> 4) * 4;
            float* p1 = accS + (qg * 2 + 1) * 4096 + sub * 256 + (l & 15) * 16 + (l >> 4) * 4;
            *(f32x4*)p0 = st.acc0[sub];
            *(f32x4*)p1 = st.acc1[sub];
        }
    }
    __syncthreads();
    if (kh == 0) {
        float e0[2][4], e1[2][4], inv[2][4], mfin[2][4], lfin[2][4];
        #pragma unroll
        for (int r = 0; r < 4; ++r) {
            int row = (l >> 4) * 4 + r;
            // group 0
            float m1v = mlS[((qg * 2 + 0) * 16 + row) * 2];
            float l1v = mlS[((qg * 2 + 0) * 16 + row) * 2 + 1];
            float mm0 = fmaxf(st.m0[r], m1v);
            float a = __builtin_amdgcn_exp2f(st.m0[r] - mm0);
            float c = __builtin_amdgcn_exp2f(m1v - mm0);
            float lm = st.sum0[r] * a + l1v * c;
            e0[0][r] = a; e1[0][r] = c; inv[0][r] = 1.f / lm;
            mfin[0][r] = mm0; lfin[0][r] = lm;
            // group 1
            float m1w = mlS[((qg * 2 + 1) * 16 + row) * 2];
            float l1w = mlS[((qg * 2 + 1) * 16 + row) * 2 + 1];
            float mm1 = fmaxf(st.m1[r], m1w);
            float a1 = __builtin_amdgcn_exp2f(st.m1[r] - mm1);
            float c1 = __builtin_amdgcn_exp2f(m1w - mm1);
            float lm1 = st.sum1[r] * a1 + l1w * c1;
            e0[1][r] = a1; e1[1][r] = c1; inv[1][r] = 1.f / lm1;
            mfin[1][r] = mm1; lfin[1][r] = lm1;
        }
        unsigned short* orow = Opart + (size_t)half * 16384 * 256 +
                               (size_t)(b * 4096 + qbase) * 256;
        #pragma unroll
        for (int sub = 0; sub < 16; ++sub) {
            f32x4 o1a = *(const f32x4*)(accS + (qg * 2 + 0) * 4096 + sub * 256 + (l & 15) * 16 + (l >> 4) * 4);
            f32x4 o1b = *(const f32x4*)(accS + (qg * 2 + 1) * 4096 + sub * 256 + (l & 15) * 16 + (l >> 4) * 4);
            #pragma unroll
            for (int r = 0; r < 4; ++r) {
                int row0 = (l >> 4) * 4 + r;
                float v0 = (st.acc0[sub][r] * e0[0][r] + o1a[r] * e1[0][r]) * inv[0][r];
                float v1 = (st.acc1[sub][r] * e0[1][r] + o1b[r] * e1[1][r]) * inv[1][r];
                orow[(size_t)row0 * 256 + sub * 16 + (l & 15)] = f2bf(v0);
                orow[(size_t)(16 + row0) * 256 + sub * 16 + (l & 15)] = f2bf(v1);
            }
        }
        if ((l & 15) == 0) {
            #pragma unroll
            for (int g = 0; g < 2; ++g) {
                #pragma unroll
                for (int r = 0; r < 4; ++r) {
                    size_t row = (size_t)(b * 4096 + qbase + g * 16 + (l >> 4) * 4 + r);
                    ml[row * 4 + half * 2]     = mfin[g][r];
                    ml[row * 4 + half * 2 + 1] = lfin[g][r];
                }
            }
        }
    }
}

// ---------------------------------------------------------------------------
// K5b: combine the two kv-halves: O = w1*O1 + w2*O2, wi = 2^(mi-m) * li / Z.
// ---------------------------------------------------------------------------
__global__ __launch_bounds__(256) void k_combine(const unsigned short* __restrict__ Opart,
        const float* __restrict__ ml, unsigned short* __restrict__ Ot) {
    int gid = blockIdx.x * 256 + threadIdx.x;   // 524288 threads: row = gid>>5, 8 cols each
    int row = gid >> 5;
    int c0 = (gid & 31) * 8;
    float m1 = ml[row * 4], l1 = ml[row * 4 + 1];
    float m2 = ml[row * 4 + 2], l2 = ml[row * 4 + 3];
    float m = fmaxf(m1, m2);
    float a1 = __builtin_amdgcn_exp2f(m1 - m) * l1;
    float a2 = __builtin_amdgcn_exp2f(m2 - m) * l2;
    float inv = 1.f / (a1 + a2);
    float w1 = a1 * inv, w2 = a2 * inv;
    size_t off = (size_t)row * 256 + c0;
    u16x8 o1 = *(const u16x8*)(Opart + off);
    u16x8 o2 = *(const u16x8*)(Opart + (size_t)16384 * 256 + off);
    u16x8 o;
    #pragma unroll
    for (int j = 0; j < 8; ++j) o[j] = f2bf(w1 * bf2f(o1[j]) + w2 * bf2f(o2[j]));
    *(u16x8*)(Ot + off) = o;
}

// ---------------------------------------------------------------------------
// K6: proj GEMM + bias + residual. out(b,c,n) = w_proj @ attn_out + b_proj + xn.
// ---------------------------------------------------------------------------
__global__ __launch_bounds__(256) void k_proj(const unsigned short* __restrict__ Ot,
        const unsigned short* __restrict__ wp, const float* __restrict__ bproj,
        const float* __restrict__ xn, float* __restrict__ out) {
    __shared__ __align__(16) char smem[65536];
    char* Asm = smem;
    char* Bsm = smem + 32768;
    int t = threadIdx.x, l = t & 63, w = t >> 6;
    int mb = blockIdx.x * 64, nb = blockIdx.y * 64;
    #pragma unroll
    for (int i = 0; i < 8; ++i) {
        int idx = (w * 8 + i) * 64 + l;
        int r = idx >> 5, p = idx & 31;
        gload16(Ot + (size_t)(mb + r) * 256 + ((p ^ (r & 7)) * 8), Asm + (w * 8 + i) * 1024);
    }
    #pragma unroll
    for (int i = 0; i < 8; ++i) {
        int idx = (w * 8 + i) * 64 + l;
        int r = idx >> 5, p = idx & 31;
        gload16(wp + (size_t)(nb + r) * 256 + ((p ^ (r & 7)) * 8), Bsm + (w * 8 + i) * 1024);
    }
    __syncthreads();
    int arow = w * 16 + (l & 15);
    bf16x8 af[8];
    #pragma unroll
    for (int ks = 0; ks < 8; ++ks)
        af[ks] = *(const bf16x8*)(Asm + arow * 512 + (((ks * 4 + (l >> 4)) ^ (arow & 7)) << 4));
    f32x4 acc[4];
    #pragma unroll
    for (int i = 0; i < 4; ++i) acc[i] = f32x4{0.f, 0.f, 0.f, 0.f};
    #pragma unroll
    for (int sub = 0; sub < 4; ++sub) {
        int brow = sub * 16 + (l & 15);
        #pragma unroll
        for (int ks = 0; ks < 8; ++ks) {
            bf16x8 bb = *(const bf16x8*)(Bsm + brow * 512 + (((ks * 4 + (l >> 4)) ^ (brow & 7)) << 4));
            acc[sub] = mfma16(af[ks], bb, acc[sub]);
        }
    }
    __syncthreads();  // all waves done reading A/B tiles; reuse LDS for transpose
    float* tr = (float*)smem;  // [64][68] f32
    #pragma unroll
    for (int sub = 0; sub < 4; ++sub) {
        int o = sub * 16 + (l & 15);
        *(f32x4*)(tr + o * 68 + w * 16 + (l >> 4) * 4) = acc[sub];
    }
    __syncthreads();
    int b = mb >> 12;
    int nloc = mb & 4095;
    #pragma unroll
    for (int it = 0; it < 4; ++it) {
        int e = it * 256 + t;
        int o = e >> 4, m4 = (e & 15) * 4;
        f32x4 v = *(const f32x4*)(tr + o * 68 + m4);
        float bv = bproj[nb + o];
        size_t off = ((size_t)(b * 256 + nb + o)) * 4096 + nloc + m4;
        float4 xx = *(const float4*)(xn + off);
        float4 ov;
        ov.x = v[0] + bv + xx.x;
        ov.y = v[1] + bv + xx.y;
        ov.z = v[2] + bv + xx.z;
        ov.w = v[3] + bv + xx.w;
        *(float4*)(out + off) = ov;
    }
}

// ---------------------------------------------------------------------------
extern "C" void kernel_launch(void* const* d_in, const int* in_sizes, int n_in,
                              void* d_out, int out_size, void* d_ws, size_t ws_size,
                              hipStream_t stream) {
    const float* x      = (const float*)d_in[0];
    const float* nscale = (const float*)d_in[1];
    const float* nbias  = (const float*)d_in[2];
    const float* wqkv   = (const float*)d_in[3];
    const float* wproj  = (const float*)d_in[4];
    const float* bproj  = (const float*)d_in[5];
    float* out = (float*)d_out;

    char* ws = (char*)d_ws;
    float* stats = (float*)ws;                                        // 1 KB
    float* xn    = (float*)(ws + 4096);                               // 16 MB fp32 (b,c,n)
    unsigned short* xnT = (unsigned short*)(ws + 4096 + 16777216);    // 8 MB bf16 (b,n,c)
    unsigned short* wq  = (unsigned short*)(ws + 4096 + 16777216 + 8388608);  // 384 KB
    unsigned short* wp  = wq + 768 * 256;                             // 128 KB
    unsigned short* qkvT = wp + 256 * 256;                            // 24 MB bf16 (b,n,768)
    unsigned short* vT   = qkvT + (size_t)16384 * 768;                // 8 MB bf16 (b,c,n)
    unsigned short* Opart = vT + (size_t)4 * 256 * 4096;              // 16 MB bf16 (2,16384,256)
    float* ml = (float*)(Opart + (size_t)2 * 16384 * 256);            // 256 KB
    unsigned short* Ot   = xnT;  // alias: xnT dead after k_qkv

    hipLaunchKernelGGL(k_wconv,   dim3(1024),       dim3(256), 0, stream, wqkv, wproj, wq, wp);
    hipLaunchKernelGGL(k_gnstats, dim3(128),        dim3(256), 0, stream, x, stats);
    hipLaunchKernelGGL(k_gnapply, dim3(64, 4, 4),   dim3(256), 0, stream, x, nscale, nbias, stats, xn, xnT);
    hipLaunchKernelGGL(k_qkv,     dim3(256, 12),    dim3(256), 0, stream, xnT, wq, qkvT);
    hipLaunchKernelGGL(k_vtrans,  dim3(64, 4, 4),   dim3(256), 0, stream, qkvT, vT);
    hipLaunchKernelGGL(k_attn,    dim3(256),        dim3(512), 0, stream, qkvT, vT, Opart, ml);
    hipLaunchKernelGGL(k_combine, dim3(2048),       dim3(256), 0, stream, Opart, ml, Ot);
    hipLaunchKernelGGL(k_proj,    dim3(256, 4),     dim3(256), 0, stream, Ot, wp, bproj, xn, out);
}